// Round 1
// baseline (12.756 us; speedup 1.0000x reference)
//
#include <hip/hip_runtime.h>

#define PH 7
#define PW 7
#define IMG_H 512
#define IMG_W 512
#define IMG_C 256
#define SCALE 1.0f

__global__ void roi_pool_kernel(const float* __restrict__ img,
                                const float* __restrict__ roi,
                                float* __restrict__ out) {
    // One block per output pixel (py, px); threads = channels.
    const int p  = blockIdx.x;       // 0..48
    const int py = p / PW;
    const int px = p % PW;
    const int c  = threadIdx.x;      // 0..255

    // ROI: [batch, x_min, y_min, x_max, y_max]; jnp.round == rintf (half-to-even)
    const int x_min = (int)rintf(roi[1] * SCALE);
    const int y_min = (int)rintf(roi[2] * SCALE);
    const int x_max = (int)rintf(roi[3] * SCALE);
    const int y_max = (int)rintf(roi[4] * SCALE);

    const float h = (float)(y_max - y_min + 1);
    const float w = (float)(x_max - x_min + 1);

    int iy = y_min + (int)floorf((float)py * (h / (float)PH));
    int ix = x_min + (int)floorf((float)px * (w / (float)PW));
    iy = min(max(iy, y_min), y_max);
    ix = min(max(ix, x_min), x_max);

    // img is NHWC (1, 512, 512, 256); out is NCHW (1, 256, 7, 7)
    const float v = img[((size_t)iy * IMG_W + ix) * IMG_C + c];
    out[(size_t)c * (PH * PW) + p] = v;
}

extern "C" void kernel_launch(void* const* d_in, const int* in_sizes, int n_in,
                              void* d_out, int out_size, void* d_ws, size_t ws_size,
                              hipStream_t stream) {
    const float* img = (const float*)d_in[0];
    const float* roi = (const float*)d_in[1];
    float* out = (float*)d_out;

    roi_pool_kernel<<<PH * PW, IMG_C, 0, stream>>>(img, roi, out);
}

// Round 2
// 11.708 us; speedup vs baseline: 1.0895x; 1.0895x over previous
//
#include <hip/hip_runtime.h>

#define PH 7
#define PW 7
#define IMG_H 512
#define IMG_W 512
#define IMG_C 256
#define SCALE 1.0f

__global__ __launch_bounds__(64) void roi_pool_kernel(const float* __restrict__ img,
                                                      const float* __restrict__ roi,
                                                      float* __restrict__ out) {
    // One block (one wave) per output pixel (py, px); each lane handles 4 channels.
    const int p    = blockIdx.x;      // 0..48
    const int py   = p / PW;
    const int px   = p % PW;
    const int lane = threadIdx.x;     // 0..63

    // ROI: [batch, x_min, y_min, x_max, y_max]; jnp.round == rintf (half-to-even)
    const int x_min = (int)rintf(roi[1] * SCALE);
    const int y_min = (int)rintf(roi[2] * SCALE);
    const int x_max = (int)rintf(roi[3] * SCALE);
    const int y_max = (int)rintf(roi[4] * SCALE);

    const float h = (float)(y_max - y_min + 1);
    const float w = (float)(x_max - x_min + 1);

    int iy = y_min + (int)floorf((float)py * (h / (float)PH));
    int ix = x_min + (int)floorf((float)px * (w / (float)PW));
    iy = min(max(iy, y_min), y_max);
    ix = min(max(ix, x_min), x_max);

    // img is NHWC (1, 512, 512, 256): pixel row of 256 ch is 1 KB contiguous.
    const float4* src = (const float4*)(img + ((size_t)iy * IMG_W + ix) * IMG_C);
    const float4 v = src[lane];       // global_load_dwordx4, coalesced 1 KB/wave

    // out is NCHW (1, 256, 7, 7): out[c*49 + p]
    const int c0 = lane * 4;
    out[(size_t)(c0 + 0) * (PH * PW) + p] = v.x;
    out[(size_t)(c0 + 1) * (PH * PW) + p] = v.y;
    out[(size_t)(c0 + 2) * (PH * PW) + p] = v.z;
    out[(size_t)(c0 + 3) * (PH * PW) + p] = v.w;
}

extern "C" void kernel_launch(void* const* d_in, const int* in_sizes, int n_in,
                              void* d_out, int out_size, void* d_ws, size_t ws_size,
                              hipStream_t stream) {
    const float* img = (const float*)d_in[0];
    const float* roi = (const float*)d_in[1];
    float* out = (float*)d_out;

    roi_pool_kernel<<<PH * PW, 64, 0, stream>>>(img, roi, out);
}